// Round 8
// baseline (83612.726 us; speedup 1.0000x reference)
//
#include <hip/hip_runtime.h>
#include <math.h>

#define Bn 512
#define Tn 256
#define Hn 512
#define Vn 7
#define BH (Bn*Hn)          // 262144
#define NLP (Bn*Tn*Vn)      // 917504

#define NBLK 256
#define NTHR 512
#define NGRP 16             // bt groups (independent batch-row groups)
#define GBLK 16             // blocks per group (jt)
#define CNT_STRIDE 32       // ints; 128B per counter line

// ARITHMETIC IS FROZEN to the round-1/5 order (the only order that passed):
// per-half k ascending 0..255 step 4, fmaf .x.y.z.w, half-combine via LDS,
// exact epilogue/logit/softmax expression trees, libm expf/tanhf/logf.

__device__ __forceinline__ float sigf(float x){ return 1.0f/(1.0f + expf(-x)); }

__device__ __forceinline__ void group_barrier(int* cnt, int target){
    __syncthreads();
    if (threadIdx.x == 0){
        __hip_atomic_fetch_add(cnt, 1, __ATOMIC_RELEASE, __HIP_MEMORY_SCOPE_AGENT);
        while (__hip_atomic_load(cnt, __ATOMIC_ACQUIRE, __HIP_MEMORY_SCOPE_AGENT) < target)
            __builtin_amdgcn_s_sleep(2);
    }
    __syncthreads();
}

__global__ void init_kernel(float* lp, int* cnts){
    int i = blockIdx.x*blockDim.x + threadIdx.x;
    if (i < NGRP) cnts[i*CNT_STRIDE] = 0;
    for (int x = i; x < NLP; x += (int)(gridDim.x*blockDim.x)) lp[x] = 0.0f;
}

// grid 256 x 512. block tile: 32 b x 32 j x 4 gates. Two 256-thread K-halves.
// W streamed L2->regs (2-group pipeline); A double-buffered in LDS, 64-k chunks.
__global__ void __launch_bounds__(NTHR, 2)
decoder_rnn_kernel(const float* __restrict__ h0, const float* __restrict__ c0,
                   const float* __restrict__ tgt, const float* __restrict__ Wih,
                   const float* __restrict__ Whh, const float* __restrict__ bih,
                   const float* __restrict__ bhh, const float* __restrict__ Wout,
                   const float* __restrict__ bout, float* out, float* ws)
{
    __shared__ float A_lds[2][2][32*68];   // [hf][buf][row*68+k], pad 64+4
    __shared__ float red[256*20];
    __shared__ float hn_lds[32*33];
    __shared__ float wihl[128*8];          // [lr=gi*32+tn][v]
    __shared__ float bihl[128], bhhl[128];
    __shared__ float woutl[7][32];
    __shared__ float boutl[8];
    __shared__ int   idx_lds[32];

    float* hbuf = ws;                  // 2*BH ping-pong h
    float* cws  = ws + 2*BH;           // BH c-state
    int*   cnts = (int*)(ws + 3*BH);   // NGRP padded counters
    float* lp   = out;                 // logits -> logp in place

    const int bt = blockIdx.x & 15;    // group: blocks {bt, bt+16, ...} share XCD
    const int jt = blockIdx.x >> 4;
    const int b0 = bt << 5;
    const int j0 = jt << 5;
    const int hf  = threadIdx.x >> 8;
    const int tid = threadIdx.x & 255;
    const int tb  = tid & 7;
    const int tn  = tid >> 3;          // 0..31
    int* cnt = cnts + bt*CNT_STRIDE;

    // A staging map (K-half offset hf*256 applied at every global A load!)
    const int ar = tid >> 3;           // row 0..31
    const int as = (tid & 7) << 3;     // col 0,8,..56 within the half's 64-chunk

    // ---- one-time preloads (same VALUES as global reads; order preserved) ----
    for (int idx = threadIdx.x; idx < 128*Vn; idx += NTHR){
        const int lr = idx / Vn, v = idx % Vn;
        wihl[lr*8 + v] = Wih[(((lr>>5)<<9) + j0 + (lr&31))*Vn + v];
    }
    for (int idx = threadIdx.x; idx < 128; idx += NTHR){
        const int R = ((idx>>5)<<9) + j0 + (idx&31);
        bihl[idx] = bih[R]; bhhl[idx] = bhh[R];
    }
    // bound 32*8 so the 8-stride decode covers jj=0..31 (round-6 bugfix)
    for (int idx = threadIdx.x; idx < 32*8; idx += NTHR){
        const int jj = idx >> 3, v = idx & 7;
        if (v < Vn) woutl[v][jj] = Wout[(long)v*Hn + j0 + jj];
    }
    if (threadIdx.x < Vn) boutl[threadIdx.x] = bout[threadIdx.x];

    // per-block state init: h rows (redundant x16, benign), own c patch
    #pragma unroll
    for (int i = 0; i < 8; ++i){
        const int f = threadIdx.x + (i << 9);
        const int r = f >> 7, c4 = f & 127;
        *(float4*)(hbuf + (long)(b0 + r)*Hn + (c4 << 2)) =
            *(const float4*)(h0 + (long)(b0 + r)*Hn + (c4 << 2));
    }
    if (threadIdx.x < 256){
        const int r = threadIdx.x >> 3, c4 = threadIdx.x & 7;
        *(float4*)(cws + (long)(b0 + r)*Hn + j0 + (c4 << 2)) =
            *(const float4*)(c0 + (long)(b0 + r)*Hn + j0 + (c4 << 2));
    }
    __syncthreads();

    // fixed W row pointers: wv[i] = Whh[(i<<9)+j0+tn][hf*256 + k]
    const float* wp[4];
    #pragma unroll
    for (int i = 0; i < 4; ++i)
        wp[i] = Whh + (long)((i<<9) + j0 + tn)*Hn + (hf<<8);

    int aoffs[4];
    #pragma unroll
    for (int i = 0; i < 4; ++i) aoffs[i] = (tb + 8*i)*68;

    for (int t = 0; t < Tn; ++t){
        const float* hprev = hbuf + (t & 1)*BH;
        float*       hnext = hbuf + ((t + 1) & 1)*BH;

        // W pipeline prologue: groups 0,1
        float4 wbuf0[4], wbuf1[4];
        #pragma unroll
        for (int i = 0; i < 4; ++i) wbuf0[i] = *(const float4*)(wp[i] + 0);
        #pragma unroll
        for (int i = 0; i < 4; ++i) wbuf1[i] = *(const float4*)(wp[i] + 4);

        // A chunk 0 prefetch — FIX: include this half's K offset (hf<<8)
        float4 a0 = *(const float4*)(hprev + (long)(b0 + ar)*Hn + (hf<<8) + as);
        float4 a1 = *(const float4*)(hprev + (long)(b0 + ar)*Hn + (hf<<8) + as + 4);

        // argmax -> one-hot index (frozen)
        if (threadIdx.x < 32){
            const int  bl = threadIdx.x;
            const long b  = b0 + bl;
            float best; int am = 0;
            if (t == 0){
                const float* xp = tgt + (b*Tn)*Vn;
                best = xp[0];
                #pragma unroll
                for (int v = 1; v < Vn; ++v){ float xv = xp[v]; if (xv > best){ best = xv; am = v; } }
            } else {
                const float* xp = lp + (b*Tn + (t-1))*Vn;
                best = xp[0] + boutl[0];
                #pragma unroll
                for (int v = 1; v < Vn; ++v){ float xv = xp[v] + boutl[v]; if (xv > best){ best = xv; am = v; } }
            }
            idx_lds[bl] = am;
        }

        // stage chunk 0
        *(float4*)(&A_lds[hf][0][ar*68 + as])     = a0;
        *(float4*)(&A_lds[hf][0][ar*68 + as + 4]) = a1;
        __syncthreads();

        float acc[4][4];
        #pragma unroll
        for (int a = 0; a < 4; ++a)
            #pragma unroll
            for (int g = 0; g < 4; ++g) acc[a][g] = 0.0f;

        for (int c = 0; c < 4; ++c){
            const float* Ab = &A_lds[hf][c & 1][0];
            if (c < 3){   // FIX: include (hf<<8) in the next-chunk A prefetch
                a0 = *(const float4*)(hprev + (long)(b0 + ar)*Hn + (hf<<8) + ((c+1)<<6) + as);
                a1 = *(const float4*)(hprev + (long)(b0 + ar)*Hn + (hf<<8) + ((c+1)<<6) + as + 4);
            }
            const float* wpc0 = wp[0] + (c<<6);
            const float* wpc1 = wp[1] + (c<<6);
            const float* wpc2 = wp[2] + (c<<6);
            const float* wpc3 = wp[3] + (c<<6);
            #pragma unroll
            for (int g = 0; g < 16; ++g){
                const int kk = g << 2;
                float4 av[4];
                #pragma unroll
                for (int i = 0; i < 4; ++i)
                    av[i] = *(const float4*)(Ab + aoffs[i] + kk);
                float4 wv[4];
                #pragma unroll
                for (int i = 0; i < 4; ++i)
                    wv[i] = (g & 1) ? wbuf1[i] : wbuf0[i];
                // prefetch group G+2 (continuous k; skip only past end of half)
                if (c < 3 || g < 14){
                    if (g & 1){
                        wbuf1[0] = *(const float4*)(wpc0 + kk + 8);
                        wbuf1[1] = *(const float4*)(wpc1 + kk + 8);
                        wbuf1[2] = *(const float4*)(wpc2 + kk + 8);
                        wbuf1[3] = *(const float4*)(wpc3 + kk + 8);
                    } else {
                        wbuf0[0] = *(const float4*)(wpc0 + kk + 8);
                        wbuf0[1] = *(const float4*)(wpc1 + kk + 8);
                        wbuf0[2] = *(const float4*)(wpc2 + kk + 8);
                        wbuf0[3] = *(const float4*)(wpc3 + kk + 8);
                    }
                }
                // frozen FMA order
                #pragma unroll
                for (int bi = 0; bi < 4; ++bi)
                    #pragma unroll
                    for (int gi = 0; gi < 4; ++gi){
                        float s = acc[bi][gi];
                        s = fmaf(av[bi].x, wv[gi].x, s);
                        s = fmaf(av[bi].y, wv[gi].y, s);
                        s = fmaf(av[bi].z, wv[gi].z, s);
                        s = fmaf(av[bi].w, wv[gi].w, s);
                        acc[bi][gi] = s;
                    }
            }
            if (c < 3){
                *(float4*)(&A_lds[hf][(c+1) & 1][ar*68 + as])     = a0;
                *(float4*)(&A_lds[hf][(c+1) & 1][ar*68 + as + 4]) = a1;
            }
            __syncthreads();
        }

        // half-combine (frozen)
        if (hf == 1){
            #pragma unroll
            for (int bi = 0; bi < 4; ++bi)
                *(float4*)(&red[tid*20 + bi*4]) =
                    make_float4(acc[bi][0], acc[bi][1], acc[bi][2], acc[bi][3]);
        }
        __syncthreads();

        // epilogue (frozen expressions; LDS-cached params = same values)
        if (hf == 0){
            #pragma unroll
            for (int bi = 0; bi < 4; ++bi){
                float4 r4 = *(const float4*)(&red[tid*20 + bi*4]);
                const int bl = tb + 8*bi;
                const long b = b0 + bl;
                const int j  = j0 + tn;
                const int ix = idx_lds[bl];
                float g4[4] = { acc[bi][0] + r4.x, acc[bi][1] + r4.y,
                                acc[bi][2] + r4.z, acc[bi][3] + r4.w };
                #pragma unroll
                for (int gi = 0; gi < 4; ++gi){
                    const int lr = (gi<<5) + tn;
                    g4[gi] += wihl[lr*8 + ix] + bihl[lr] + bhhl[lr];
                }
                const float iv = sigf(g4[0]);
                const float fv = sigf(g4[1]);
                const float gv = tanhf(g4[2]);
                const float ov = sigf(g4[3]);
                const float cold = cws[b*Hn + j];
                const float cn = fv*cold + iv*gv;
                cws[b*Hn + j] = cn;
                const float hn = ov * tanhf(cn);
                hnext[b*Hn + j] = hn;
                hn_lds[bl*33 + tn] = hn;
            }
        }
        __syncthreads();

        // partial logits, 32x7 threads over our 32 j (frozen)
        if (threadIdx.x < 224){
            const int bl = threadIdx.x / 7;
            const int v  = threadIdx.x % 7;
            float s = 0.0f;
            #pragma unroll
            for (int jj = 0; jj < 32; ++jj)
                s = fmaf(hn_lds[bl*33 + jj], woutl[v][jj], s);
            atomicAdd(&lp[((long)(b0 + bl)*Tn + t)*Vn + v], s);
        }

        group_barrier(cnt, GBLK*(t+1));
    }

    // ---- final: hT/cT (group-local slice) + log_softmax (frozen) ----
    {
        const int li = (jt << 10) + (threadIdx.x << 1);   // 16 blk x 1024 = 32x512
        const int r = li >> 9, cc = li & 511;
        *(float2*)(out + NLP + (long)(b0 + r)*Hn + cc) =
            *(const float2*)(hbuf + (long)(b0 + r)*Hn + cc);   // T even -> buf 0
        *(float2*)(out + NLP + BH + (long)(b0 + r)*Hn + cc) =
            *(const float2*)(cws + (long)(b0 + r)*Hn + cc);
    }
    {
        const int  rl  = (jt << 9) + threadIdx.x;          // 8192 group rows
        const long row = (long)(b0 + (rl >> 8))*Tn + (rl & 255);
        float x[Vn]; float m = -INFINITY;
        #pragma unroll
        for (int v = 0; v < Vn; ++v){ x[v] = lp[row*Vn + v] + boutl[v]; m = fmaxf(m, x[v]); }
        float s = 0.0f;
        #pragma unroll
        for (int v = 0; v < Vn; ++v) s += expf(x[v] - m);
        const float ls = logf(s);
        #pragma unroll
        for (int v = 0; v < Vn; ++v) lp[row*Vn + v] = x[v] - m - ls;
    }
}

extern "C" void kernel_launch(void* const* d_in, const int* in_sizes, int n_in,
                              void* d_out, int out_size, void* d_ws, size_t ws_size,
                              hipStream_t stream) {
    const float* h0   = (const float*)d_in[0];
    const float* c0   = (const float*)d_in[1];
    const float* tgt  = (const float*)d_in[2];
    const float* Wih  = (const float*)d_in[3];
    const float* Whh  = (const float*)d_in[4];
    const float* bih  = (const float*)d_in[5];
    const float* bhh  = (const float*)d_in[6];
    const float* Wout = (const float*)d_in[7];
    const float* bout = (const float*)d_in[8];
    float* out = (float*)d_out;
    float* ws  = (float*)d_ws;               // 3*BH floats + counters
    int*   cnts = (int*)(ws + 3*BH);

    init_kernel<<<256, 256, 0, stream>>>(out, cnts);

    void* args[] = { &h0, &c0, &tgt, &Wih, &Whh, &bih, &bhh, &Wout, &bout, &out, &ws };
    (void)hipLaunchCooperativeKernel((const void*)decoder_rnn_kernel,
                               dim3(NBLK), dim3(NTHR), args, 0, stream);
}

// Round 9
// 10238.936 us; speedup vs baseline: 8.1662x; 8.1662x over previous
//
#include <hip/hip_runtime.h>
#include <math.h>

#define Bn 512
#define Tn 256
#define Hn 512
#define Vn 7
#define BH (Bn*Hn)          // 262144
#define NLP (Bn*Tn*Vn)      // 917504

#define NBLK 256
#define NTHR 512
#define NGRP 16             // independent batch-row groups (32 b each)
#define GBLK 16             // blocks per group (j-tiles)
#define CNT_STRIDE 32       // ints; 128B per counter line

// ARITHMETIC IS FROZEN to the round-1/5 order (verified absmax 0.0):
// per-half k ascending (hf*256 ..), quads .x.y.z.w, half-combine via LDS,
// exact epilogue/logit/softmax expression trees, libm expf/tanhf/logf.
// W moves global->reg->LDS in per-chunk BURSTS (round-8 lesson: trickling W
// through registers across the step thrashes per-XCD L2 -> 298 GB HBM).

__device__ __forceinline__ float sigf(float x){ return 1.0f/(1.0f + expf(-x)); }

__device__ __forceinline__ void group_barrier(int* cnt, int target){
    __syncthreads();
    if (threadIdx.x == 0){
        __hip_atomic_fetch_add(cnt, 1, __ATOMIC_RELEASE, __HIP_MEMORY_SCOPE_AGENT);
        // relaxed polls (no per-poll cache invalidate), one acquire at exit
        while (__hip_atomic_load(cnt, __ATOMIC_RELAXED, __HIP_MEMORY_SCOPE_AGENT) < target)
            __builtin_amdgcn_s_sleep(1);
        (void)__hip_atomic_load(cnt, __ATOMIC_ACQUIRE, __HIP_MEMORY_SCOPE_AGENT);
    }
    __syncthreads();
}

__global__ void init_kernel(float* lp, int* cnts){
    int i = blockIdx.x*blockDim.x + threadIdx.x;
    if (i < NGRP) cnts[i*CNT_STRIDE] = 0;
    for (int x = i; x < NLP; x += (int)(gridDim.x*blockDim.x)) lp[x] = 0.0f;
}

// grid 256 x 512. block tile: 32 b x 32 j x 4 gates (round-5 tiling).
// two 256-thread K-halves; per chunk: float4 reg-prefetch -> LDS -> compute.
__global__ void __launch_bounds__(NTHR, 2)
decoder_rnn_kernel(const float* __restrict__ h0, const float* __restrict__ c0,
                   const float* __restrict__ tgt, const float* __restrict__ Wih,
                   const float* __restrict__ Whh, const float* __restrict__ bih,
                   const float* __restrict__ bhh, const float* __restrict__ Wout,
                   const float* __restrict__ bout, float* out, float* ws)
{
    __shared__ float A_lds[2][32*36];
    __shared__ float W_lds[2][128*36];
    __shared__ float hn_lds[32*33];
    __shared__ int   idx_lds[32];

    float* hbuf = ws;                  // 2*BH ping-pong h
    float* cws  = ws + 2*BH;           // BH c-state
    int*   cnts = (int*)(ws + 3*BH);   // NGRP padded counters
    float* lp   = out;                 // logits -> logp in place

    const int bt = blockIdx.x & 15;    // group: all 16 j-blocks of bt share an XCD
    const int jt = blockIdx.x >> 4;
    const int b0 = bt << 5;
    const int j0 = jt << 5;
    const int hf  = threadIdx.x >> 8;     // K-half 0/1
    const int tid = threadIdx.x & 255;
    const int tb  = tid & 7;              // b_local = tb + 8*bi
    const int tn  = tid >> 3;             // j within tile (0..31)
    int* cnt = cnts + bt*CNT_STRIDE;

    const int gtid = blockIdx.x*NTHR + threadIdx.x;
    const int nthr = NBLK*NTHR;

    // ---- per-block state init (verbatim round 5) ----
    #pragma unroll
    for (int i = 0; i < 8; ++i){
        const int f = threadIdx.x + (i << 9);
        const int r = f >> 7, c4 = f & 127;
        *(float4*)(hbuf + (long)(b0 + r)*Hn + (c4 << 2)) =
            *(const float4*)(h0 + (long)(b0 + r)*Hn + (c4 << 2));
    }
    if (threadIdx.x < 256){
        const int r = threadIdx.x >> 3, c4 = threadIdx.x & 7;
        *(float4*)(cws + (long)(b0 + r)*Hn + j0 + (c4 << 2)) =
            *(const float4*)(c0 + (long)(b0 + r)*Hn + j0 + (c4 << 2));
    }
    __syncthreads();

    for (int t = 0; t < Tn; ++t){
        const float* hprev = hbuf + (t & 1)*BH;
        float*       hnext = hbuf + ((t + 1) & 1)*BH;

        // ---- argmax -> one-hot index (frozen) ----
        if (threadIdx.x < 32){
            const int  bl = threadIdx.x;
            const long b  = b0 + bl;
            float best; int am = 0;
            if (t == 0){
                const float* xp = tgt + (b*Tn)*Vn;
                best = xp[0];
                #pragma unroll
                for (int v = 1; v < Vn; ++v){ float xv = xp[v]; if (xv > best){ best = xv; am = v; } }
            } else {
                const float* xp = lp + (b*Tn + (t-1))*Vn;
                best = xp[0] + bout[0];
                #pragma unroll
                for (int v = 1; v < Vn; ++v){ float xv = xp[v] + bout[v]; if (xv > best){ best = xv; am = v; } }
            }
            idx_lds[bl] = am;
        }

        float acc[4][4];
        #pragma unroll
        for (int a = 0; a < 4; ++a)
            #pragma unroll
            for (int g = 0; g < 4; ++g) acc[a][g] = 0.0f;

        // ---- prefetch chunk 0 into regs (verbatim round 5) ----
        float4 wreg[4], areg;
        {
            const int k0 = hf << 8;
            #pragma unroll
            for (int i = 0; i < 4; ++i){
                const int f = tid + (i << 8);
                const int r = f >> 3, c4 = f & 7;
                const int gi = r >> 5, jj = r & 31;
                wreg[i] = *(const float4*)(Whh + (long)((gi<<9) + j0 + jj)*Hn + k0 + (c4 << 2));
            }
            areg = *(const float4*)(hprev + (long)(b0 + (tid >> 3))*Hn + k0 + ((tid & 7) << 2));
        }

        for (int c = 0; c < 8; ++c){
            __syncthreads();
            #pragma unroll
            for (int i = 0; i < 4; ++i){
                const int f = tid + (i << 8);
                const int r = f >> 3, c4 = f & 7;
                *(float4*)(&W_lds[hf][r*36 + (c4 << 2)]) = wreg[i];
            }
            *(float4*)(&A_lds[hf][(tid >> 3)*36 + ((tid & 7) << 2)]) = areg;
            __syncthreads();
            if (c < 7){
                const int k0 = (hf << 8) + ((c + 1) << 5);
                #pragma unroll
                for (int i = 0; i < 4; ++i){
                    const int f = tid + (i << 8);
                    const int r = f >> 3, c4 = f & 7;
                    const int gi = r >> 5, jj = r & 31;
                    wreg[i] = *(const float4*)(Whh + (long)((gi<<9) + j0 + jj)*Hn + k0 + (c4 << 2));
                }
                areg = *(const float4*)(hprev + (long)(b0 + (tid >> 3))*Hn + k0 + ((tid & 7) << 2));
            }
            // ---- compute chunk c (frozen order) ----
            #pragma unroll 2
            for (int k = 0; k < 32; k += 4){
                float4 av[4], wv[4];
                #pragma unroll
                for (int i = 0; i < 4; ++i)
                    av[i] = *reinterpret_cast<const float4*>(&A_lds[hf][(tb + 8*i)*36 + k]);
                #pragma unroll
                for (int i = 0; i < 4; ++i)
                    wv[i] = *reinterpret_cast<const float4*>(&W_lds[hf][((i<<5) + tn)*36 + k]);
                #pragma unroll
                for (int bi = 0; bi < 4; ++bi)
                    #pragma unroll
                    for (int gi = 0; gi < 4; ++gi){
                        float s = acc[bi][gi];
                        s = fmaf(av[bi].x, wv[gi].x, s);
                        s = fmaf(av[bi].y, wv[gi].y, s);
                        s = fmaf(av[bi].z, wv[gi].z, s);
                        s = fmaf(av[bi].w, wv[gi].w, s);
                        acc[bi][gi] = s;
                    }
            }
        }

        // ---- reduce the two K-halves (frozen) ----
        float* red = &W_lds[0][0];
        if (hf == 1){
            #pragma unroll
            for (int bi = 0; bi < 4; ++bi)
                *reinterpret_cast<float4*>(&red[tid*20 + bi*4]) =
                    make_float4(acc[bi][0], acc[bi][1], acc[bi][2], acc[bi][3]);
        }
        __syncthreads();

        // ---- epilogue (frozen) ----
        if (hf == 0){
            #pragma unroll
            for (int bi = 0; bi < 4; ++bi){
                float4 r4 = *reinterpret_cast<const float4*>(&red[tid*20 + bi*4]);
                const int bl = tb + 8*bi;
                const long b = b0 + bl;
                const int j  = j0 + tn;
                const int ix = idx_lds[bl];
                float g4[4] = { acc[bi][0] + r4.x, acc[bi][1] + r4.y,
                                acc[bi][2] + r4.z, acc[bi][3] + r4.w };
                #pragma unroll
                for (int gi = 0; gi < 4; ++gi){
                    const int r = (gi<<9) + j;
                    g4[gi] += Wih[r*Vn + ix] + bih[r] + bhh[r];
                }
                const float iv = sigf(g4[0]);
                const float fv = sigf(g4[1]);
                const float gv = tanhf(g4[2]);
                const float ov = sigf(g4[3]);
                const float cold = cws[b*Hn + j];
                const float cn = fv*cold + iv*gv;
                cws[b*Hn + j] = cn;
                const float hn = ov * tanhf(cn);
                hnext[b*Hn + j] = hn;
                hn_lds[bl*33 + tn] = hn;
            }
        }
        __syncthreads();

        // ---- partial logits (frozen) ----
        if (threadIdx.x < 224){
            const int bl = threadIdx.x / 7;
            const int v  = threadIdx.x % 7;
            const float* wo = Wout + v*Hn + j0;
            float s = 0.0f;
            #pragma unroll
            for (int jj = 0; jj < 32; ++jj)
                s = fmaf(hn_lds[bl*33 + jj], wo[jj], s);
            atomicAdd(&lp[((long)(b0 + bl)*Tn + t)*Vn + v], s);
        }

        group_barrier(cnt, GBLK*(t+1));
    }

    // ---- final: hT, cT, in-place log_softmax (frozen) ----
    for (int i = gtid; i < BH; i += nthr){
        out[NLP + i]      = hbuf[i];   // T=256 even -> final h in buffer 0
        out[NLP + BH + i] = cws[i];
    }
    {
        const long row = gtid;         // exactly B*T rows
        float x[Vn]; float m = -INFINITY;
        #pragma unroll
        for (int v = 0; v < Vn; ++v){ x[v] = lp[row*Vn + v] + bout[v]; m = fmaxf(m, x[v]); }
        float s = 0.0f;
        #pragma unroll
        for (int v = 0; v < Vn; ++v) s += expf(x[v] - m);
        const float ls = logf(s);
        #pragma unroll
        for (int v = 0; v < Vn; ++v) lp[row*Vn + v] = x[v] - m - ls;
    }
}

extern "C" void kernel_launch(void* const* d_in, const int* in_sizes, int n_in,
                              void* d_out, int out_size, void* d_ws, size_t ws_size,
                              hipStream_t stream) {
    const float* h0   = (const float*)d_in[0];
    const float* c0   = (const float*)d_in[1];
    const float* tgt  = (const float*)d_in[2];
    const float* Wih  = (const float*)d_in[3];
    const float* Whh  = (const float*)d_in[4];
    const float* bih  = (const float*)d_in[5];
    const float* bhh  = (const float*)d_in[6];
    const float* Wout = (const float*)d_in[7];
    const float* bout = (const float*)d_in[8];
    float* out = (float*)d_out;
    float* ws  = (float*)d_ws;               // 3*BH floats + counters
    int*   cnts = (int*)(ws + 3*BH);

    init_kernel<<<256, 256, 0, stream>>>(out, cnts);

    void* args[] = { &h0, &c0, &tgt, &Wih, &Whh, &bih, &bhh, &Wout, &bout, &out, &ws };
    (void)hipLaunchCooperativeKernel((const void*)decoder_rnn_kernel,
                               dim3(NBLK), dim3(NTHR), args, 0, stream);
}